// Round 5
// baseline (112.758 us; speedup 1.0000x reference)
//
#include <hip/hip_runtime.h>
#include <math.h>

#define BB 16
#define AA 262144
#define GG 128
#define TPB 256
#define NBLK (AA / TPB)   // 1024 block-columns, 1 anchor per thread
#define IPB 8             // images per block (grid.y = BB/IPB = 2)

// ws layout (floats):
//   [0 .. BB*NBLK)           per-image per-block l1 sums   (sum[b*NBLK + blk])
//   [BB*NBLK .. 2*BB*NBLK)   per-image per-block fg counts

__global__ __launch_bounds__(TPB) void loss_main_kernel(
    const float4* __restrict__ reg,    // [B*A]
    const float4* __restrict__ anc,    // [A]
    const float4* __restrict__ gt,     // [B*G]
    const int*   __restrict__ mi,      // [B*A]
    float* __restrict__ ws_sum,        // [BB*NBLK]
    float* __restrict__ ws_cnt)        // [BB*NBLK]
{
    __shared__ float4 gts[IPB * GG];   // 16 KB: (cx, cy, log w, log h)
    __shared__ float redS[IPB * 4];
    __shared__ float redC[IPB * 4];

    const int t    = threadIdx.x;
    const int bx   = blockIdx.x;
    const int half = blockIdx.y;       // which 8-image slab
    const int b0   = half * IPB;

    // stage this slab's gt boxes, pre-transformed (16 KB, 4 vec4/thread)
#pragma unroll
    for (int i = 0; i < (IPB * GG) / TPB; ++i) {
        const float4 g = gt[b0 * GG + i * TPB + t];
        const float w = g.z - g.x;
        const float h = g.w - g.y;
        gts[i * TPB + t] = make_float4(g.x + 0.5f * w, g.y + 0.5f * h,
                                       __logf(w), __logf(h));
    }

    // per-anchor invariants (independent of LDS -> overlaps staging)
    const int a = bx * TPB + t;
    const float4 an = anc[a];
    const float ex_w  = an.z - an.x;
    const float ex_h  = an.w - an.y;
    const float ex_cx = an.x + 0.5f * ex_w;
    const float ex_cy = an.y + 0.5f * ex_h;
    const float inv_w = 1.0f / ex_w;
    const float inv_h = 1.0f / ex_h;
    const float lw    = __logf(ex_w);
    const float lh    = __logf(ex_h);

    // prefetch everything for this slab: 8 scalar + 8 vec4 loads in flight
    int    mjv[IPB];
    float4 r[IPB];
#pragma unroll
    for (int j = 0; j < IPB; ++j) mjv[j] = mi[(b0 + j) * AA + a];
#pragma unroll
    for (int j = 0; j < IPB; ++j) r[j] = reg[(b0 + j) * AA + a];

    __syncthreads();   // gts ready

    const int wv   = t >> 6;
    const int lane = t & 63;

#pragma unroll
    for (int j = 0; j < IPB; ++j) {
        const int mj = mjv[j];
        const float4 g = gts[j * GG + (mj < 0 ? 0 : mj)];

        const float dx = (g.x - ex_cx) * inv_w;
        const float dy = (g.y - ex_cy) * inv_h;
        const float dw = g.z - lw;
        const float dh = g.w - lh;

        const float l1 = fabsf(r[j].x - dx) + fabsf(r[j].y - dy) +
                         fabsf(r[j].z - dw) + fabsf(r[j].w - dh);
        float s = (mj >= 0) ? l1 : 0.0f;

        const unsigned long long bal = __ballot(mj >= 0);
#pragma unroll
        for (int o = 32; o > 0; o >>= 1) s += __shfl_down(s, o);

        if (lane == 0) {
            redS[j * 4 + wv] = s;
            redC[j * 4 + wv] = (float)__popcll(bal);
        }
    }
    __syncthreads();

    if (t < IPB) {
        const float s = redS[t * 4] + redS[t * 4 + 1] +
                        redS[t * 4 + 2] + redS[t * 4 + 3];
        const float c = redC[t * 4] + redC[t * 4 + 1] +
                        redC[t * 4 + 2] + redC[t * 4 + 3];
        ws_sum[(b0 + t) * NBLK + bx] = s;
        ws_cnt[(b0 + t) * NBLK + bx] = c;
    }
}

// single block: each wave reduces 4 images, thread 0 combines
__global__ __launch_bounds__(TPB) void reduce_final_kernel(
    const float* __restrict__ ws_sum,
    const float* __restrict__ ws_cnt,
    float* __restrict__ out)
{
    __shared__ float per_img[BB];
    const int t    = threadIdx.x;
    const int wv   = t >> 6;
    const int lane = t & 63;

#pragma unroll
    for (int k = 0; k < 4; ++k) {
        const int b = wv * 4 + k;
        float s = 0.0f, c = 0.0f;
#pragma unroll
        for (int i = 0; i < NBLK / 64; ++i) {
            s += ws_sum[b * NBLK + i * 64 + lane];
            c += ws_cnt[b * NBLK + i * 64 + lane];
        }
#pragma unroll
        for (int o = 32; o > 0; o >>= 1) {
            s += __shfl_down(s, o);
            c += __shfl_down(c, o);
        }
        if (lane == 0) per_img[b] = s / fmaxf(1.0f, c);
    }
    __syncthreads();

    if (t == 0) {
        float acc = 0.0f;
#pragma unroll
        for (int b = 0; b < BB; ++b) acc += per_img[b];
        out[0] = acc / (float)BB;
    }
}

extern "C" void kernel_launch(void* const* d_in, const int* in_sizes, int n_in,
                              void* d_out, int out_size, void* d_ws, size_t ws_size,
                              hipStream_t stream) {
    const float4* reg = (const float4*)d_in[0];   // bbox_regression [B,A,4]
    const float4* anc = (const float4*)d_in[1];   // anchors [A,4]
    const float4* gt  = (const float4*)d_in[2];   // gt_boxes [B,G,4]
    const int*    mi  = (const int*)d_in[3];      // matched_idxs [B,A]

    float* ws_sum = (float*)d_ws;
    float* ws_cnt = ws_sum + BB * NBLK;

    dim3 grid(NBLK, BB / IPB);
    loss_main_kernel<<<grid, TPB, 0, stream>>>(reg, anc, gt, mi, ws_sum, ws_cnt);
    reduce_final_kernel<<<1, TPB, 0, stream>>>(ws_sum, ws_cnt, (float*)d_out);
}